// Round 1
// baseline (1209.349 us; speedup 1.0000x reference)
//
#include <hip/hip_runtime.h>
#include <math.h>

// Problem constants
#define BB 8
#define TT 512
#define EE 64
#define HH 512
#define VV 32000
#define MM 4096      // B*T
#define G3 1536      // 3*H

typedef _Float16 half8 __attribute__((ext_vector_type(8)));
typedef float floatx4 __attribute__((ext_vector_type(4)));

// ---------------------------------------------------------------------------
// async global->LDS 16B copy (wave-uniform LDS base + lane*16 scatter)
__device__ __forceinline__ void gld_lds16(const _Float16* g, _Float16* l) {
    __builtin_amdgcn_global_load_lds(
        (const __attribute__((address_space(1))) void*)(const void*)g,
        (__attribute__((address_space(3))) void*)(void*)l, 16, 0, 0);
}

// ---------------------------------------------------------------------------
// W [K][N] fp32  ->  Wt [N][K] fp16   (LDS-tiled transpose, 32x32 tiles)
__global__ __launch_bounds__(256) void transpose_f32_f16(
    const float* __restrict__ W, _Float16* __restrict__ Wt, int K, int N)
{
    __shared__ float tile[32][33];
    const int n0 = blockIdx.x * 32;
    const int k0 = blockIdx.y * 32;
    const int tx = threadIdx.x, ty = threadIdx.y;   // 32 x 8
    #pragma unroll
    for (int i = 0; i < 32; i += 8)
        tile[ty + i][tx] = W[(k0 + ty + i) * N + n0 + tx];
    __syncthreads();
    #pragma unroll
    for (int i = 0; i < 32; i += 8)
        Wt[(n0 + ty + i) * K + k0 + tx] = (_Float16)tile[tx][ty + i];
}

// ---------------------------------------------------------------------------
// x[(t*B+b)*E + e] = emb[ids[b*T + t]*E + e]  (fp16, t-major rows for layer 1)
__global__ __launch_bounds__(256) void gather_embed(
    const int* __restrict__ ids, const float* __restrict__ emb,
    _Float16* __restrict__ x)
{
    const int tid = blockIdx.x * 256 + threadIdx.x;   // M*E threads
    const int m = tid >> 6, e = tid & 63;
    const int t = m >> 3, b = m & 7;
    const int id = ids[b * TT + t];
    x[tid] = (_Float16)emb[id * EE + e];
}

// ---------------------------------------------------------------------------
// MFMA fp16 GEMM:  C[M][N] = A[M][K] * Bt[N][K]^T + bias[N]   (fp32 out)
// 128x128 tile, BK=64, 256 thr = 2x2 waves of 64x64, XOR-swizzled LDS.
__global__ __launch_bounds__(256) void gemm_f16(
    const _Float16* __restrict__ A, const _Float16* __restrict__ Bt,
    const float* __restrict__ bias, float* __restrict__ C,
    int Ndim, int Kdim)
{
    __shared__ _Float16 As[128 * 64];   // [row][granule^ (row&7)] granule=8 f16
    __shared__ _Float16 Bs[128 * 64];

    const int n0 = blockIdx.x * 128;
    const int m0 = blockIdx.y * 128;
    const int tid = threadIdx.x;
    const int wid = tid >> 6;
    const int lane = tid & 63;
    const int wm = wid & 1, wn = wid >> 1;
    const int quad = lane >> 4, rlo = lane & 15;

    floatx4 acc[4][4] = {};

    for (int k0 = 0; k0 < Kdim; k0 += 64) {
        __syncthreads();   // previous compute done before LDS overwrite
        #pragma unroll
        for (int i = 0; i < 4; ++i) {
            const int sbase = wid * 256 + i * 64;       // wave-uniform granule base
            const int slot = sbase + lane;              // this lane's granule
            const int r = slot >> 3;                    // tile row 0..127
            const int p = slot & 7;                     // stored granule position
            const int srcg = p ^ (r & 7);               // XOR swizzle source
            gld_lds16(A  + (m0 + r) * Kdim + k0 + srcg * 8, As + sbase * 8);
            gld_lds16(Bt + (n0 + r) * Kdim + k0 + srcg * 8, Bs + sbase * 8);
        }
        __syncthreads();   // compiler emits s_waitcnt vmcnt(0) before s_barrier

        #pragma unroll
        for (int kk = 0; kk < 64; kk += 32) {
            const int gi = (kk >> 3) + quad;            // wanted granule index
            half8 af[4], bf[4];
            #pragma unroll
            for (int mi = 0; mi < 4; ++mi) {
                const int ra = wm * 64 + mi * 16 + rlo;
                af[mi] = *(const half8*)(As + (ra * 8 + (gi ^ (ra & 7))) * 8);
            }
            #pragma unroll
            for (int ni = 0; ni < 4; ++ni) {
                const int rb = wn * 64 + ni * 16 + rlo;
                bf[ni] = *(const half8*)(Bs + (rb * 8 + (gi ^ (rb & 7))) * 8);
            }
            #pragma unroll
            for (int mi = 0; mi < 4; ++mi)
                #pragma unroll
                for (int ni = 0; ni < 4; ++ni)
                    acc[mi][ni] = __builtin_amdgcn_mfma_f32_16x16x32_f16(
                        af[mi], bf[ni], acc[mi][ni], 0, 0, 0);
        }
    }

    // Epilogue. C/D mapping: col = lane&15, row = quad*4 + reg  (verified m89/m91)
    #pragma unroll
    for (int ni = 0; ni < 4; ++ni) {
        const int gn = n0 + wn * 64 + ni * 16 + rlo;
        const float bv = bias[gn];
        #pragma unroll
        for (int mi = 0; mi < 4; ++mi) {
            const int gm = m0 + wm * 64 + mi * 16 + quad * 4;
            #pragma unroll
            for (int r = 0; r < 4; ++r)
                C[(gm + r) * Ndim + gn] = acc[mi][ni][r] + bv;
        }
    }
}

// ---------------------------------------------------------------------------
// QRNN fo-pool. g[(t*B+b)*3H + {h, H+h, 2H+h}] = {z,f,o} preactivations (fp32).
// out fp16 at index b*base_mult + h + t*t_stride.
//   layer1: base_mult=H,   t_stride=B*H  -> t-major rows (feeds GEMM2)
//   layer2: base_mult=T*H, t_stride=H    -> b-major rows (feeds projection)
__global__ __launch_bounds__(64) void fo_pool(
    const float* __restrict__ g, _Float16* __restrict__ hout,
    int base_mult, int t_stride)
{
    const int tid = blockIdx.x * 64 + threadIdx.x;   // 0..4095
    const int b = tid >> 9, h = tid & 511;
    const float* gp = g + b * G3 + h;
    int oidx = b * base_mult + h;
    float c = 0.f;
    #pragma unroll 4
    for (int t = 0; t < TT; ++t) {
        const float zz = gp[0];
        const float ff = gp[HH];
        const float oo = gp[2 * HH];
        const float z = tanhf(zz);
        const float f = 1.f / (1.f + expf(-ff));
        const float o = 1.f / (1.f + expf(-oo));
        c = f * c + (1.f - f) * z;
        hout[oidx] = (_Float16)(o * c);
        gp += BB * G3;
        oidx += t_stride;
    }
}

// ---------------------------------------------------------------------------
extern "C" void kernel_launch(void* const* d_in, const int* in_sizes, int n_in,
                              void* d_out, int out_size, void* d_ws, size_t ws_size,
                              hipStream_t stream) {
    (void)in_sizes; (void)n_in; (void)out_size; (void)ws_size;
    const int*   ids = (const int*)d_in[0];
    const float* emb = (const float*)d_in[1];
    const float* W1  = (const float*)d_in[2];
    const float* b1  = (const float*)d_in[3];
    const float* W2  = (const float*)d_in[4];
    const float* b2  = (const float*)d_in[5];
    const float* Wp  = (const float*)d_in[6];
    const float* bp  = (const float*)d_in[7];
    float* out = (float*)d_out;

    // workspace layout (256B-aligned offsets), ~68.6 MB total
    char* ws = (char*)d_ws;
    _Float16* x_h  = (_Float16*)(ws);                 // 4096*64   fp16
    _Float16* W1t  = (_Float16*)(ws + 524288);        // 1536*64   fp16 [N][K]
    _Float16* W2t  = (_Float16*)(ws + 720896);        // 1536*512  fp16 [N][K]
    _Float16* Wpt  = (_Float16*)(ws + 2293760);       // 32000*512 fp16 [N][K]
    float*    gbuf = (float*)   (ws + 35061760);      // 4096*1536 fp32 (reused)
    _Float16* h1   = (_Float16*)(ws + 60227584);      // 4096*512  fp16
    _Float16* h2   = (_Float16*)(ws + 64421888);      // 4096*512  fp16

    transpose_f32_f16<<<dim3(G3 / 32, EE / 32), dim3(32, 8), 0, stream>>>(W1, W1t, EE, G3);
    transpose_f32_f16<<<dim3(G3 / 32, HH / 32), dim3(32, 8), 0, stream>>>(W2, W2t, HH, G3);
    transpose_f32_f16<<<dim3(VV / 32, HH / 32), dim3(32, 8), 0, stream>>>(Wp, Wpt, HH, VV);
    gather_embed<<<MM * EE / 256, 256, 0, stream>>>(ids, emb, x_h);

    gemm_f16<<<dim3(G3 / 128, MM / 128), 256, 0, stream>>>(x_h, W1t, b1, gbuf, G3, EE);
    fo_pool<<<64, 64, 0, stream>>>(gbuf, h1, HH, BB * HH);
    gemm_f16<<<dim3(G3 / 128, MM / 128), 256, 0, stream>>>(h1, W2t, b2, gbuf, G3, HH);
    fo_pool<<<64, 64, 0, stream>>>(gbuf, h2, TT * HH, HH);
    gemm_f16<<<dim3(VV / 128, MM / 128), 256, 0, stream>>>(h2, Wpt, bp, out, VV, HH);
}